// Round 7
// baseline (390.374 us; speedup 1.0000x reference)
//
#include <hip/hip_runtime.h>

// Problem constants (fixed by setup_inputs)
#define BATCH 4
#define DDIM 256
#define LLEN 4096
#define NTOK (BATCH * LLEN)   // 16384
#define KCODE 8192
#define COMMITMENT 0.25f
#define MARGIN 0.02f          // dot-units; ~9 sigma of bf16 sim-error diff
#define CAP 48                // candidate slots per token

typedef __attribute__((ext_vector_type(8))) short short8;
typedef __attribute__((ext_vector_type(8))) unsigned short ushort8;
typedef __attribute__((ext_vector_type(4))) float f32x4;

__device__ __forceinline__ unsigned short f2bf(float f) {
  unsigned u = __float_as_uint(f);
  unsigned r = (u + 0x7fffu + ((u >> 16) & 1u)) >> 16;
  return (unsigned short)r;
}

// ---------------------------------------------------------------------------
// P1: transpose x [B,D,L] -> xT fp32 [N,D] and xt_frag bf16 (MFMA frag order).
// Also zero count/loss accumulators. Block = 64 tokens.
// Frag order (row n, dim d): off = (n>>4)*4096 + (d>>5)*512
//                                  + (((d>>3)&3)*16 + (n&15))*8 + (d&7)
// ---------------------------------------------------------------------------
__global__ __launch_bounds__(256) void prep_x_kernel(
    const float* __restrict__ x, float* __restrict__ xT,
    unsigned short* __restrict__ xtf, int* __restrict__ count,
    float* __restrict__ lossac) {
  __shared__ float As[256 * 65];
  const int tid = threadIdx.x;
  const int n0 = blockIdx.x * 64;
  const int b = n0 >> 12, l0 = n0 & 4095;
  const float* xb = x + ((size_t)b << 20) + l0;
  {
    const int t4 = (tid & 15) * 4, dof = tid >> 4;
#pragma unroll
    for (int p = 0; p < 16; ++p) {
      int d = p * 16 + dof;
      float4 v = *(const float4*)(xb + (size_t)d * LLEN + t4);
      As[d * 65 + t4 + 0] = v.x;
      As[d * 65 + t4 + 1] = v.y;
      As[d * 65 + t4 + 2] = v.z;
      As[d * 65 + t4 + 3] = v.w;
    }
  }
  __syncthreads();
  const int tok = tid >> 2, sub = tid & 3;
  const int n = n0 + tok;
#pragma unroll
  for (int q = 0; q < 16; ++q) {
    int d = q * 16 + sub * 4;
    float4 v = make_float4(As[(d + 0) * 65 + tok], As[(d + 1) * 65 + tok],
                           As[(d + 2) * 65 + tok], As[(d + 3) * 65 + tok]);
    *(float4*)(xT + (size_t)n * 256 + d) = v;
  }
#pragma unroll
  for (int q = 0; q < 8; ++q) {
    int d = (sub + q * 4) * 8;
    ushort8 u;
#pragma unroll
    for (int e = 0; e < 8; ++e) u[e] = f2bf(As[(d + e) * 65 + tok]);
    size_t off = ((size_t)(n >> 4)) * 4096 + q * 512 + (sub * 16 + (n & 15)) * 8;
    *(ushort8*)(xtf + off) = u;
  }
  if (tid < 64) count[n0 + tid] = 0;
  if (blockIdx.x == 0 && tid == 0) *lossac = 0.0f;
}

// ---------------------------------------------------------------------------
// P2: codebook -> normalized bf16 frags (rnorm folded in) + rnorm fp32.
// Block = 64 codes, 4 threads per code.
// ---------------------------------------------------------------------------
__global__ __launch_bounds__(256) void prep_cb_kernel(
    const float* __restrict__ cb, unsigned short* __restrict__ cbf,
    float* __restrict__ rnorm) {
  const int tid = threadIdx.x;
  const int k = blockIdx.x * 64 + (tid >> 2), sub = tid & 3;
  const float* row = cb + (size_t)k * 256;
  float s = 0.0f;
#pragma unroll
  for (int q = 0; q < 8; ++q) {
    int d = (sub + q * 4) * 8;
    float4 v0 = *(const float4*)(row + d);
    float4 v1 = *(const float4*)(row + d + 4);
    s += v0.x * v0.x + v0.y * v0.y + v0.z * v0.z + v0.w * v0.w;
    s += v1.x * v1.x + v1.y * v1.y + v1.z * v1.z + v1.w * v1.w;
  }
  s += __shfl_xor(s, 1);
  s += __shfl_xor(s, 2);
  float rn = 1.0f / sqrtf(fmaxf(s, 1e-24f));
  if (sub == 0) rnorm[k] = rn;
#pragma unroll
  for (int q = 0; q < 8; ++q) {
    int d = (sub + q * 4) * 8;
    float4 v0 = *(const float4*)(row + d);
    float4 v1 = *(const float4*)(row + d + 4);
    ushort8 u;
    u[0] = f2bf(v0.x * rn); u[1] = f2bf(v0.y * rn);
    u[2] = f2bf(v0.z * rn); u[3] = f2bf(v0.w * rn);
    u[4] = f2bf(v1.x * rn); u[5] = f2bf(v1.y * rn);
    u[6] = f2bf(v1.z * rn); u[7] = f2bf(v1.w * rn);
    size_t off = ((size_t)(k >> 4)) * 4096 + q * 512 + (sub * 16 + (k & 15)) * 8;
    *(ushort8*)(cbf + off) = u;
  }
}

// ---------------------------------------------------------------------------
// Fused sim scan, v3. Grid (NTOK/64, 2): block = 64 tokens x one 4096-code
// HALF (key change vs v2: 512 blocks -> 2 blocks/CU -> 2 waves/SIMD; v2's
// 256-block grid pinned the kernel at 1 wave/SIMD, exposing every L2-load
// and admission-VALU bubble to the MFMA pipe).
// Per block: A-fragments in registers, B streamed global->VGPR from
// L2-resident cbf (depth-3 prefetch, no per-iter barriers). Seed phase:
// max-only over the half's first 512 codes, cross-lane + cross-wave (LDS)
// combined. Main scan: admit code if sim > rmax - MARGIN (running max,
// cross-lane combined per 256-code group). The true argmax (in its half)
// always satisfies this for MARGIN > 2*bf16err; rescore picks it exactly.
// ---------------------------------------------------------------------------
__device__ __forceinline__ void crosslane_max(float (&rmax)[16]) {
#pragma unroll
  for (int ir = 0; ir < 16; ++ir) {
    float v = rmax[ir];
    v = fmaxf(v, __shfl_xor(v, 1));
    v = fmaxf(v, __shfl_xor(v, 2));
    v = fmaxf(v, __shfl_xor(v, 4));
    v = fmaxf(v, __shfl_xor(v, 8));
    rmax[ir] = v;
  }
}

__device__ __forceinline__ void admit_and_track(
    const f32x4 (&acc)[4][4], float (&rmax)[16], int grp, int code0, int w,
    int lane, int n0, int* __restrict__ count, int* __restrict__ cand) {
  const int codebase = code0 + grp * 256 + w * 64 + (lane & 15);
  const int tokbase = n0 + ((lane >> 4) << 2);
#pragma unroll
  for (int i = 0; i < 4; ++i) {
#pragma unroll
    for (int j = 0; j < 4; ++j) {
      bool p0 = acc[i][j][0] > rmax[i * 4 + 0] - MARGIN;
      bool p1 = acc[i][j][1] > rmax[i * 4 + 1] - MARGIN;
      bool p2 = acc[i][j][2] > rmax[i * 4 + 2] - MARGIN;
      bool p3 = acc[i][j][3] > rmax[i * 4 + 3] - MARGIN;
      if (__any((int)(p0 | p1 | p2 | p3))) {
#pragma unroll
        for (int r = 0; r < 4; ++r) {
          if (acc[i][j][r] > rmax[i * 4 + r] - MARGIN) {
            int token = tokbase + i * 16 + r;
            int code = codebase + j * 16;
            int slot = atomicAdd(&count[token], 1);
            if (slot < CAP) cand[(size_t)token * CAP + slot] = code;
          }
        }
      }
#pragma unroll
      for (int r = 0; r < 4; ++r)
        rmax[i * 4 + r] = fmaxf(rmax[i * 4 + r], acc[i][j][r]);
    }
  }
  crosslane_max(rmax);
}

__global__ __launch_bounds__(256, 2) void simfused_kernel(
    const unsigned short* __restrict__ xtf,
    const unsigned short* __restrict__ cbf, int* __restrict__ count,
    int* __restrict__ cand) {
  __shared__ unsigned int LBs[64];
  const int tid = threadIdx.x;
  const int w = tid >> 6, lane = tid & 63;
  const int n0 = blockIdx.x * 64;
  const int code0 = blockIdx.y * 4096;  // this block's code half
  if (tid < 64) LBs[tid] = 0u;

  // A-fragments resident in registers: 4 token-tiles x 8 k-chunks.
  short8 afr[4][8];
  {
    const unsigned short* ab = xtf + ((size_t)(n0 >> 4)) * 4096 + lane * 8;
#pragma unroll
    for (int i = 0; i < 4; ++i)
#pragma unroll
      for (int c = 0; c < 8; ++c)
        afr[i][c] = *(const short8*)(ab + i * 4096 + c * 512);
  }

  // B base for this wave's quarter (tiles w*4..w*4+3 of each 16-tile group)
  // within this block's half. Iteration it: grp=it>>3, c=it&7; frag j at
  // bbase + (grp*16 + j)*4096 + c*512.
  const unsigned short* bbase =
      cbf + (size_t)(blockIdx.y * 256 + w * 4) * 4096 + lane * 8;

  short8 bf[4][4];  // rotating prefetch buffers, depth 3
  f32x4 acc0[4][4], acc1[4][4];
  float rmax[16];
#pragma unroll
  for (int ir = 0; ir < 16; ++ir) rmax[ir] = -1e30f;

  // ---- Phase 1: seed scan, local groups 0..1 (512 codes), max-only ----
#pragma unroll
  for (int pre = 0; pre < 3; ++pre)
#pragma unroll
    for (int j = 0; j < 4; ++j)
      bf[pre][j] = *(const short8*)(bbase + j * 4096 + pre * 512);

  for (int it = 0; it < 16; ++it) {
    const int pit = it + 3;
    if (pit < 16) {
      const int pg = pit >> 3, pc = pit & 7;
      const unsigned short* bb = bbase + (size_t)pg * 16 * 4096 + pc * 512;
#pragma unroll
      for (int j = 0; j < 4; ++j)
        bf[(it + 3) & 3][j] = *(const short8*)(bb + j * 4096);
    }
    const int c = it & 7;
    if (c == 0) {
#pragma unroll
      for (int i = 0; i < 4; ++i)
#pragma unroll
        for (int j = 0; j < 4; ++j)
          acc0[i][j] = __builtin_amdgcn_mfma_f32_16x16x32_bf16(
              afr[i][c], bf[it & 3][j], (f32x4){0.f, 0.f, 0.f, 0.f}, 0, 0, 0);
    } else {
#pragma unroll
      for (int i = 0; i < 4; ++i)
#pragma unroll
        for (int j = 0; j < 4; ++j)
          acc0[i][j] = __builtin_amdgcn_mfma_f32_16x16x32_bf16(
              afr[i][c], bf[it & 3][j], acc0[i][j], 0, 0, 0);
    }
    if (c == 7) {
#pragma unroll
      for (int i = 0; i < 4; ++i)
#pragma unroll
        for (int j = 0; j < 4; ++j)
#pragma unroll
          for (int r = 0; r < 4; ++r)
            rmax[i * 4 + r] = fmaxf(rmax[i * 4 + r], acc0[i][j][r]);
    }
  }
  crosslane_max(rmax);
  __syncthreads();  // LBs init visible
  if ((lane & 15) == 0) {
#pragma unroll
    for (int ir = 0; ir < 16; ++ir) {
      int tl = (ir >> 2) * 16 + ((lane >> 4) << 2) + (ir & 3);
      atomicMax(&LBs[tl], __float_as_uint(rmax[ir]));
    }
  }
  __syncthreads();
#pragma unroll
  for (int ir = 0; ir < 16; ++ir) {
    int tl = (ir >> 2) * 16 + ((lane >> 4) << 2) + (ir & 3);
    rmax[ir] = __uint_as_float(LBs[tl]);
  }

  // ---- Phase 2: full scan of the half (16 local groups) with admission ----
#pragma unroll
  for (int pre = 0; pre < 3; ++pre)
#pragma unroll
    for (int j = 0; j < 4; ++j)
      bf[pre][j] = *(const short8*)(bbase + j * 4096 + pre * 512);

  for (int gg = 0; gg < 8; ++gg) {
#pragma unroll
    for (int s = 0; s < 16; ++s) {
      const int it = gg * 16 + s;
      const int pit = it + 3;
      if (pit < 128) {
        const int pg = pit >> 3, pc = pit & 7;
        const unsigned short* bb = bbase + (size_t)pg * 16 * 4096 + pc * 512;
#pragma unroll
        for (int j = 0; j < 4; ++j)
          bf[(s + 3) & 3][j] = *(const short8*)(bb + j * 4096);
      }
      const int c = s & 7;
      if (s < 8) {
        if (s == 0) {
#pragma unroll
          for (int i = 0; i < 4; ++i)
#pragma unroll
            for (int j = 0; j < 4; ++j)
              acc0[i][j] = __builtin_amdgcn_mfma_f32_16x16x32_bf16(
                  afr[i][c], bf[s & 3][j], (f32x4){0.f, 0.f, 0.f, 0.f}, 0, 0, 0);
        } else {
#pragma unroll
          for (int i = 0; i < 4; ++i)
#pragma unroll
            for (int j = 0; j < 4; ++j)
              acc0[i][j] = __builtin_amdgcn_mfma_f32_16x16x32_bf16(
                  afr[i][c], bf[s & 3][j], acc0[i][j], 0, 0, 0);
        }
      } else {
        if (s == 8) {
#pragma unroll
          for (int i = 0; i < 4; ++i)
#pragma unroll
            for (int j = 0; j < 4; ++j)
              acc1[i][j] = __builtin_amdgcn_mfma_f32_16x16x32_bf16(
                  afr[i][c], bf[s & 3][j], (f32x4){0.f, 0.f, 0.f, 0.f}, 0, 0, 0);
        } else {
#pragma unroll
          for (int i = 0; i < 4; ++i)
#pragma unroll
            for (int j = 0; j < 4; ++j)
              acc1[i][j] = __builtin_amdgcn_mfma_f32_16x16x32_bf16(
                  afr[i][c], bf[s & 3][j], acc1[i][j], 0, 0, 0);
        }
      }
      if (s == 7)
        admit_and_track(acc0, rmax, 2 * gg, code0, w, lane, n0, count, cand);
      if (s == 15)
        admit_and_track(acc1, rmax, 2 * gg + 1, code0, w, lane, n0, count,
                        cand);
    }
  }
}

// ---------------------------------------------------------------------------
// S3: exact fp64 rescore of candidates; one wave per token. Computes
// p/sqrt(sum c^2) in double -> true argmax (error ~1e-13 << min top-2 gap).
// ---------------------------------------------------------------------------
__global__ __launch_bounds__(256) void rescore_kernel(
    const float* __restrict__ xT, const float* __restrict__ cb,
    const int* __restrict__ count, const int* __restrict__ cand,
    int* __restrict__ besti_g) {
  const int w = threadIdx.x >> 6, lane = threadIdx.x & 63;
  const int t = blockIdx.x * 4 + w;
  float4 xv = *(const float4*)(xT + (size_t)t * 256 + lane * 4);
  const double x0 = xv.x, x1 = xv.y, x2 = xv.z, x3 = xv.w;
  int cnt = min(count[t], CAP);
  double bv = -1e300;
  int bi = 1 << 30;
  for (int s = 0; s < cnt; ++s) {
    int k = cand[(size_t)t * CAP + s];
    float4 cv = *(const float4*)(cb + (size_t)k * 256 + lane * 4);
    const double c0 = cv.x, c1 = cv.y, c2 = cv.z, c3 = cv.w;
    double p = x0 * c0 + x1 * c1 + x2 * c2 + x3 * c3;
    double cc = c0 * c0 + c1 * c1 + c2 * c2 + c3 * c3;
#pragma unroll
    for (int m = 1; m < 64; m <<= 1) {
      p += __shfl_xor(p, m);
      cc += __shfl_xor(cc, m);
    }
    double v = p / sqrt(cc);
    if (v > bv || (v == bv && k < bi)) { bv = v; bi = k; }
  }
  if (lane == 0) besti_g[t] = bi;
}

// ---------------------------------------------------------------------------
// Epilogue: LDS-staged transpose-gather. Block = 64 tokens (fixed b, l0).
// ---------------------------------------------------------------------------
__global__ __launch_bounds__(256) void epilogue_kernel(
    const float* __restrict__ x, const float* __restrict__ cb,
    const float* __restrict__ rnorm, const int* __restrict__ besti_g,
    float* __restrict__ out, float* __restrict__ loss_accum) {
  __shared__ float QT[256 * 68];
  __shared__ int idxs[64];
  __shared__ float lred[4];
  const int tid = threadIdx.x;
  const int n0 = blockIdx.x * 64;
  const int b = n0 >> 12, l0 = n0 & 4095;

  if (tid < 64) idxs[tid] = besti_g[n0 + tid];
  __syncthreads();

  {
    const int t = tid >> 2, sub = tid & 3;
    const int idx = idxs[t];
    const float rn = rnorm[idx];
    const float* row = cb + (size_t)idx * 256;
#pragma unroll
    for (int p = 0; p < 16; ++p) {
      const int d = p * 16 + sub * 4;
      float4 v = *(const float4*)(row + d);
      QT[(d + 0) * 68 + t] = v.x * rn;
      QT[(d + 1) * 68 + t] = v.y * rn;
      QT[(d + 2) * 68 + t] = v.z * rn;
      QT[(d + 3) * 68 + t] = v.w * rn;
    }
  }
  __syncthreads();

  float part = 0.0f;
  {
    const int t4 = (tid & 15) * 4;
    const int d0 = tid >> 4;
#pragma unroll
    for (int p = 0; p < 16; ++p) {
      const int d = p * 16 + d0;
      const size_t o = ((size_t)(b * 256 + d) << 12) + l0 + t4;
      float4 q = *(const float4*)(&QT[d * 68 + t4]);
      float4 xv = *(const float4*)(x + o);
      *(float4*)(out + o) = q;
      float e0 = q.x - xv.x, e1 = q.y - xv.y, e2 = q.z - xv.z, e3 = q.w - xv.w;
      part += e0 * e0 + e1 * e1 + e2 * e2 + e3 * e3;
    }
  }
#pragma unroll
  for (int off = 32; off > 0; off >>= 1) part += __shfl_down(part, off);
  const int w = tid >> 6, lane = tid & 63;
  if (lane == 0) lred[w] = part;
  __syncthreads();
  if (tid == 0)
    atomicAdd(loss_accum, lred[0] + lred[1] + lred[2] + lred[3]);
}

__global__ void finalize_kernel(const float* __restrict__ loss_accum,
                                float* __restrict__ out_loss) {
  *out_loss = COMMITMENT * (*loss_accum) / (float)((size_t)NTOK * DDIM);
}

extern "C" void kernel_launch(void* const* d_in, const int* in_sizes, int n_in,
                              void* d_out, int out_size, void* d_ws,
                              size_t ws_size, hipStream_t stream) {
  const float* x = (const float*)d_in[0];   // [4,256,4096]
  const float* cb = (const float*)d_in[1];  // [8192,256]
  float* out = (float*)d_out;

  char* ws = (char*)d_ws;
  unsigned short* xtf = (unsigned short*)(ws);              // 8 MB
  unsigned short* cbf = (unsigned short*)(ws + 8388608);    // 4 MB
  float* xT = (float*)(ws + 12582912);                      // 16 MB
  int* cand = (int*)(ws + 29360128);                        // 3 MB (16384*48*4)
  float* rnorm = (float*)(ws + 32505856);                   // 32 KB
  int* count = (int*)(ws + 32538624);                       // 64 KB
  int* besti = (int*)(ws + 32604160);                       // 64 KB
  float* lossac = (float*)(ws + 32669696);                  // 4 B

  prep_x_kernel<<<NTOK / 64, 256, 0, stream>>>(x, xT, xtf, count, lossac);
  prep_cb_kernel<<<KCODE / 64, 256, 0, stream>>>(cb, cbf, rnorm);
  simfused_kernel<<<dim3(NTOK / 64, 2), 256, 0, stream>>>(xtf, cbf, count,
                                                          cand);
  rescore_kernel<<<NTOK / 4, 256, 0, stream>>>(xT, cb, count, cand, besti);
  epilogue_kernel<<<NTOK / 64, 256, 0, stream>>>(x, cb, rnorm, besti, out,
                                                 lossac);
  finalize_kernel<<<1, 1, 0, stream>>>(lossac, out + (out_size - 1));
}

// Round 9
// 266.092 us; speedup vs baseline: 1.4671x; 1.4671x over previous
//
#include <hip/hip_runtime.h>

// Problem constants (fixed by setup_inputs)
#define BATCH 4
#define DDIM 256
#define LLEN 4096
#define NTOK (BATCH * LLEN)   // 16384
#define KCODE 8192
#define COMMITMENT 0.25f
#define MARGIN 0.02f          // dot-units; ~9 sigma of bf16 sim-error diff
#define CAP 48                // candidate slots per token

typedef __attribute__((ext_vector_type(8))) short short8;
typedef __attribute__((ext_vector_type(8))) unsigned short ushort8;
typedef __attribute__((ext_vector_type(4))) float f32x4;

__device__ __forceinline__ unsigned short f2bf(float f) {
  unsigned u = __float_as_uint(f);
  unsigned r = (u + 0x7fffu + ((u >> 16) & 1u)) >> 16;
  return (unsigned short)r;
}

// ---------------------------------------------------------------------------
// P1: transpose x [B,D,L] -> xT fp32 [N,D] and xt_frag bf16 (MFMA frag order).
// Also zero count/loss accumulators. Block = 64 tokens.
// Frag order (row n, dim d): off = (n>>4)*4096 + (d>>5)*512
//                                  + (((d>>3)&3)*16 + (n&15))*8 + (d&7)
// ---------------------------------------------------------------------------
__global__ __launch_bounds__(256) void prep_x_kernel(
    const float* __restrict__ x, float* __restrict__ xT,
    unsigned short* __restrict__ xtf, int* __restrict__ count,
    float* __restrict__ lossac) {
  __shared__ float As[256 * 65];
  const int tid = threadIdx.x;
  const int n0 = blockIdx.x * 64;
  const int b = n0 >> 12, l0 = n0 & 4095;
  const float* xb = x + ((size_t)b << 20) + l0;
  {
    const int t4 = (tid & 15) * 4, dof = tid >> 4;
#pragma unroll
    for (int p = 0; p < 16; ++p) {
      int d = p * 16 + dof;
      float4 v = *(const float4*)(xb + (size_t)d * LLEN + t4);
      As[d * 65 + t4 + 0] = v.x;
      As[d * 65 + t4 + 1] = v.y;
      As[d * 65 + t4 + 2] = v.z;
      As[d * 65 + t4 + 3] = v.w;
    }
  }
  __syncthreads();
  const int tok = tid >> 2, sub = tid & 3;
  const int n = n0 + tok;
#pragma unroll
  for (int q = 0; q < 16; ++q) {
    int d = q * 16 + sub * 4;
    float4 v = make_float4(As[(d + 0) * 65 + tok], As[(d + 1) * 65 + tok],
                           As[(d + 2) * 65 + tok], As[(d + 3) * 65 + tok]);
    *(float4*)(xT + (size_t)n * 256 + d) = v;
  }
#pragma unroll
  for (int q = 0; q < 8; ++q) {
    int d = (sub + q * 4) * 8;
    ushort8 u;
#pragma unroll
    for (int e = 0; e < 8; ++e) u[e] = f2bf(As[(d + e) * 65 + tok]);
    size_t off = ((size_t)(n >> 4)) * 4096 + q * 512 + (sub * 16 + (n & 15)) * 8;
    *(ushort8*)(xtf + off) = u;
  }
  if (tid < 64) count[n0 + tid] = 0;
  if (blockIdx.x == 0 && tid == 0) *lossac = 0.0f;
}

// ---------------------------------------------------------------------------
// P2: codebook -> normalized bf16 frags (rnorm folded in) + rnorm fp32.
// Block = 64 codes, 4 threads per code.
// ---------------------------------------------------------------------------
__global__ __launch_bounds__(256) void prep_cb_kernel(
    const float* __restrict__ cb, unsigned short* __restrict__ cbf,
    float* __restrict__ rnorm) {
  const int tid = threadIdx.x;
  const int k = blockIdx.x * 64 + (tid >> 2), sub = tid & 3;
  const float* row = cb + (size_t)k * 256;
  float s = 0.0f;
#pragma unroll
  for (int q = 0; q < 8; ++q) {
    int d = (sub + q * 4) * 8;
    float4 v0 = *(const float4*)(row + d);
    float4 v1 = *(const float4*)(row + d + 4);
    s += v0.x * v0.x + v0.y * v0.y + v0.z * v0.z + v0.w * v0.w;
    s += v1.x * v1.x + v1.y * v1.y + v1.z * v1.z + v1.w * v1.w;
  }
  s += __shfl_xor(s, 1);
  s += __shfl_xor(s, 2);
  float rn = 1.0f / sqrtf(fmaxf(s, 1e-24f));
  if (sub == 0) rnorm[k] = rn;
#pragma unroll
  for (int q = 0; q < 8; ++q) {
    int d = (sub + q * 4) * 8;
    float4 v0 = *(const float4*)(row + d);
    float4 v1 = *(const float4*)(row + d + 4);
    ushort8 u;
    u[0] = f2bf(v0.x * rn); u[1] = f2bf(v0.y * rn);
    u[2] = f2bf(v0.z * rn); u[3] = f2bf(v0.w * rn);
    u[4] = f2bf(v1.x * rn); u[5] = f2bf(v1.y * rn);
    u[6] = f2bf(v1.z * rn); u[7] = f2bf(v1.w * rn);
    size_t off = ((size_t)(k >> 4)) * 4096 + q * 512 + (sub * 16 + (k & 15)) * 8;
    *(ushort8*)(cbf + off) = u;
  }
}

// ---------------------------------------------------------------------------
// Fused sim scan, v4.1. Block = 512 threads (8 waves), 64 tokens, ALL 8192
// codes (32 groups of 256 — v4's fatal bug was scanning only 16 groups).
// Wave w: token-half th=w&1 (2 i-tiles, 32 tokens), code-quarter cq=w>>1
// (4 j-tiles, 64 codes of each 256-code group). Per-wave registers:
// afr 2x8 (64 VGPR) + bf 4x4 (64) + acc 2x4 (32) + rmax[8] ~= 190 ->
// fits 2 waves/SIMD (an 8-wave block REQUIRES <=256 VGPR to be schedulable,
// so the round-7 launch_bounds spill trap is structurally avoided).
// B streams global->VGPR from L2-resident cbf, depth-3 prefetch, no
// per-iteration barriers. Seed: first 512 codes max-only + cross-lane +
// cross-wave (LDS) combine. Main: admit code if sim > rmax - MARGIN
// (running max, cross-lane combined per group) -> superset of codes within
// MARGIN of the final max; exact rescore picks the true argmax.
// ---------------------------------------------------------------------------
__device__ __forceinline__ void crosslane_max8(float (&rmax)[8]) {
#pragma unroll
  for (int ir = 0; ir < 8; ++ir) {
    float v = rmax[ir];
    v = fmaxf(v, __shfl_xor(v, 1));
    v = fmaxf(v, __shfl_xor(v, 2));
    v = fmaxf(v, __shfl_xor(v, 4));
    v = fmaxf(v, __shfl_xor(v, 8));
    rmax[ir] = v;
  }
}

__device__ __forceinline__ void admit2(
    const f32x4 (&acc)[2][4], float (&rmax)[8], int grp, int cq, int th,
    int lane, int n0, int* __restrict__ count, int* __restrict__ cand) {
  const int codebase = grp * 256 + cq * 64 + (lane & 15);
  const int tokbase = n0 + th * 32 + ((lane >> 4) << 2);
#pragma unroll
  for (int i = 0; i < 2; ++i) {
#pragma unroll
    for (int j = 0; j < 4; ++j) {
      bool p0 = acc[i][j][0] > rmax[i * 4 + 0] - MARGIN;
      bool p1 = acc[i][j][1] > rmax[i * 4 + 1] - MARGIN;
      bool p2 = acc[i][j][2] > rmax[i * 4 + 2] - MARGIN;
      bool p3 = acc[i][j][3] > rmax[i * 4 + 3] - MARGIN;
      if (__any((int)(p0 | p1 | p2 | p3))) {
#pragma unroll
        for (int r = 0; r < 4; ++r) {
          if (acc[i][j][r] > rmax[i * 4 + r] - MARGIN) {
            int token = tokbase + i * 16 + r;
            int code = codebase + j * 16;
            int slot = atomicAdd(&count[token], 1);
            if (slot < CAP) cand[(size_t)token * CAP + slot] = code;
          }
        }
      }
#pragma unroll
      for (int r = 0; r < 4; ++r)
        rmax[i * 4 + r] = fmaxf(rmax[i * 4 + r], acc[i][j][r]);
    }
  }
  crosslane_max8(rmax);
}

__global__ __launch_bounds__(512) void simfused_kernel(
    const unsigned short* __restrict__ xtf,
    const unsigned short* __restrict__ cbf, int* __restrict__ count,
    int* __restrict__ cand) {
  __shared__ unsigned int LBs[64];
  const int tid = threadIdx.x;
  const int w = tid >> 6, lane = tid & 63;
  const int th = w & 1, cq = w >> 1;
  const int n0 = blockIdx.x * 64;
  if (tid < 64) LBs[tid] = 0u;

  // A-fragments: 2 token-tiles x 8 k-chunks (64 VGPRs).
  short8 afr[2][8];
  {
    const unsigned short* ab =
        xtf + ((size_t)((n0 >> 4) + th * 2)) * 4096 + lane * 8;
#pragma unroll
    for (int i = 0; i < 2; ++i)
#pragma unroll
      for (int c = 0; c < 8; ++c)
        afr[i][c] = *(const short8*)(ab + i * 4096 + c * 512);
  }

  // B base for this wave's quarter (tiles cq*4..cq*4+3 of each 16-tile
  // group). Iteration it: grp=it>>3, c=it&7; frag j at
  // bbase + grp*16*4096 + j*4096 + c*512.
  const unsigned short* bbase = cbf + (size_t)(cq * 4) * 4096 + lane * 8;

  short8 bf[4][4];  // rotating prefetch buffers, depth 3
  f32x4 acc[2][4];
  float rmax[8];
#pragma unroll
  for (int ir = 0; ir < 8; ++ir) rmax[ir] = -1e30f;

  // ---- Phase 1: seed scan, groups 0..1 (512 codes), max-only ----
#pragma unroll
  for (int pre = 0; pre < 3; ++pre)
#pragma unroll
    for (int j = 0; j < 4; ++j)
      bf[pre][j] = *(const short8*)(bbase + j * 4096 + pre * 512);

  for (int it = 0; it < 16; ++it) {
    const int pit = it + 3;
    if (pit < 16) {
      const int pg = pit >> 3, pc = pit & 7;
      const unsigned short* bb = bbase + (size_t)pg * 16 * 4096 + pc * 512;
#pragma unroll
      for (int j = 0; j < 4; ++j)
        bf[(it + 3) & 3][j] = *(const short8*)(bb + j * 4096);
    }
    const int c = it & 7;
    if (c == 0) {
#pragma unroll
      for (int i = 0; i < 2; ++i)
#pragma unroll
        for (int j = 0; j < 4; ++j)
          acc[i][j] = __builtin_amdgcn_mfma_f32_16x16x32_bf16(
              afr[i][c], bf[it & 3][j], (f32x4){0.f, 0.f, 0.f, 0.f}, 0, 0, 0);
    } else {
#pragma unroll
      for (int i = 0; i < 2; ++i)
#pragma unroll
        for (int j = 0; j < 4; ++j)
          acc[i][j] = __builtin_amdgcn_mfma_f32_16x16x32_bf16(
              afr[i][c], bf[it & 3][j], acc[i][j], 0, 0, 0);
    }
    if (c == 7) {
#pragma unroll
      for (int i = 0; i < 2; ++i)
#pragma unroll
        for (int j = 0; j < 4; ++j)
#pragma unroll
          for (int r = 0; r < 4; ++r)
            rmax[i * 4 + r] = fmaxf(rmax[i * 4 + r], acc[i][j][r]);
    }
  }
  crosslane_max8(rmax);
  __syncthreads();  // LBs init visible
  if ((lane & 15) == 0) {
#pragma unroll
    for (int ir = 0; ir < 8; ++ir) {
      int tl = th * 32 + (ir >> 2) * 16 + ((lane >> 4) << 2) + (ir & 3);
      atomicMax(&LBs[tl], __float_as_uint(rmax[ir]));
    }
  }
  __syncthreads();
#pragma unroll
  for (int ir = 0; ir < 8; ++ir) {
    int tl = th * 32 + (ir >> 2) * 16 + ((lane >> 4) << 2) + (ir & 3);
    rmax[ir] = __uint_as_float(LBs[tl]);
  }

  // ---- Phase 2: full scan (32 groups of 256 codes) with admission ----
#pragma unroll
  for (int pre = 0; pre < 3; ++pre)
#pragma unroll
    for (int j = 0; j < 4; ++j)
      bf[pre][j] = *(const short8*)(bbase + j * 4096 + pre * 512);

  for (int g = 0; g < 32; ++g) {
#pragma unroll
    for (int s = 0; s < 8; ++s) {
      const int it = g * 8 + s;
      const int pit = it + 3;
      if (pit < 256) {
        const int pg = pit >> 3, pc = pit & 7;
        const unsigned short* bb = bbase + (size_t)pg * 16 * 4096 + pc * 512;
#pragma unroll
        for (int j = 0; j < 4; ++j)
          bf[(it + 3) & 3][j] = *(const short8*)(bb + j * 4096);
      }
      if (s == 0) {
#pragma unroll
        for (int i = 0; i < 2; ++i)
#pragma unroll
          for (int j = 0; j < 4; ++j)
            acc[i][j] = __builtin_amdgcn_mfma_f32_16x16x32_bf16(
                afr[i][s], bf[it & 3][j], (f32x4){0.f, 0.f, 0.f, 0.f}, 0, 0, 0);
      } else {
#pragma unroll
        for (int i = 0; i < 2; ++i)
#pragma unroll
          for (int j = 0; j < 4; ++j)
            acc[i][j] = __builtin_amdgcn_mfma_f32_16x16x32_bf16(
                afr[i][s], bf[it & 3][j], acc[i][j], 0, 0, 0);
      }
    }
    admit2(acc, rmax, g, cq, th, lane, n0, count, cand);
  }
}

// ---------------------------------------------------------------------------
// S3: exact fp64 rescore of candidates; one wave per token. Computes
// p/sqrt(sum c^2) in double -> true argmax (error ~1e-13 << min top-2 gap).
// ---------------------------------------------------------------------------
__global__ __launch_bounds__(256) void rescore_kernel(
    const float* __restrict__ xT, const float* __restrict__ cb,
    const int* __restrict__ count, const int* __restrict__ cand,
    int* __restrict__ besti_g) {
  const int w = threadIdx.x >> 6, lane = threadIdx.x & 63;
  const int t = blockIdx.x * 4 + w;
  float4 xv = *(const float4*)(xT + (size_t)t * 256 + lane * 4);
  const double x0 = xv.x, x1 = xv.y, x2 = xv.z, x3 = xv.w;
  int cnt = min(count[t], CAP);
  double bv = -1e300;
  int bi = 1 << 30;
  for (int s = 0; s < cnt; ++s) {
    int k = cand[(size_t)t * CAP + s];
    float4 cv = *(const float4*)(cb + (size_t)k * 256 + lane * 4);
    const double c0 = cv.x, c1 = cv.y, c2 = cv.z, c3 = cv.w;
    double p = x0 * c0 + x1 * c1 + x2 * c2 + x3 * c3;
    double cc = c0 * c0 + c1 * c1 + c2 * c2 + c3 * c3;
#pragma unroll
    for (int m = 1; m < 64; m <<= 1) {
      p += __shfl_xor(p, m);
      cc += __shfl_xor(cc, m);
    }
    double v = p / sqrt(cc);
    if (v > bv || (v == bv && k < bi)) { bv = v; bi = k; }
  }
  if (lane == 0) besti_g[t] = bi;
}

// ---------------------------------------------------------------------------
// Epilogue: LDS-staged transpose-gather. Block = 64 tokens (fixed b, l0).
// ---------------------------------------------------------------------------
__global__ __launch_bounds__(256) void epilogue_kernel(
    const float* __restrict__ x, const float* __restrict__ cb,
    const float* __restrict__ rnorm, const int* __restrict__ besti_g,
    float* __restrict__ out, float* __restrict__ loss_accum) {
  __shared__ float QT[256 * 68];
  __shared__ int idxs[64];
  __shared__ float lred[4];
  const int tid = threadIdx.x;
  const int n0 = blockIdx.x * 64;
  const int b = n0 >> 12, l0 = n0 & 4095;

  if (tid < 64) idxs[tid] = besti_g[n0 + tid];
  __syncthreads();

  {
    const int t = tid >> 2, sub = tid & 3;
    const int idx = idxs[t];
    const float rn = rnorm[idx];
    const float* row = cb + (size_t)idx * 256;
#pragma unroll
    for (int p = 0; p < 16; ++p) {
      const int d = p * 16 + sub * 4;
      float4 v = *(const float4*)(row + d);
      QT[(d + 0) * 68 + t] = v.x * rn;
      QT[(d + 1) * 68 + t] = v.y * rn;
      QT[(d + 2) * 68 + t] = v.z * rn;
      QT[(d + 3) * 68 + t] = v.w * rn;
    }
  }
  __syncthreads();

  float part = 0.0f;
  {
    const int t4 = (tid & 15) * 4;
    const int d0 = tid >> 4;
#pragma unroll
    for (int p = 0; p < 16; ++p) {
      const int d = p * 16 + d0;
      const size_t o = ((size_t)(b * 256 + d) << 12) + l0 + t4;
      float4 q = *(const float4*)(&QT[d * 68 + t4]);
      float4 xv = *(const float4*)(x + o);
      *(float4*)(out + o) = q;
      float e0 = q.x - xv.x, e1 = q.y - xv.y, e2 = q.z - xv.z, e3 = q.w - xv.w;
      part += e0 * e0 + e1 * e1 + e2 * e2 + e3 * e3;
    }
  }
#pragma unroll
  for (int off = 32; off > 0; off >>= 1) part += __shfl_down(part, off);
  const int w = tid >> 6, lane = tid & 63;
  if (lane == 0) lred[w] = part;
  __syncthreads();
  if (tid == 0)
    atomicAdd(loss_accum, lred[0] + lred[1] + lred[2] + lred[3]);
}

__global__ void finalize_kernel(const float* __restrict__ loss_accum,
                                float* __restrict__ out_loss) {
  *out_loss = COMMITMENT * (*loss_accum) / (float)((size_t)NTOK * DDIM);
}

extern "C" void kernel_launch(void* const* d_in, const int* in_sizes, int n_in,
                              void* d_out, int out_size, void* d_ws,
                              size_t ws_size, hipStream_t stream) {
  const float* x = (const float*)d_in[0];   // [4,256,4096]
  const float* cb = (const float*)d_in[1];  // [8192,256]
  float* out = (float*)d_out;

  char* ws = (char*)d_ws;
  unsigned short* xtf = (unsigned short*)(ws);              // 8 MB
  unsigned short* cbf = (unsigned short*)(ws + 8388608);    // 4 MB
  float* xT = (float*)(ws + 12582912);                      // 16 MB
  int* cand = (int*)(ws + 29360128);                        // 3 MB (16384*48*4)
  float* rnorm = (float*)(ws + 32505856);                   // 32 KB
  int* count = (int*)(ws + 32538624);                       // 64 KB
  int* besti = (int*)(ws + 32604160);                       // 64 KB
  float* lossac = (float*)(ws + 32669696);                  // 4 B

  prep_x_kernel<<<NTOK / 64, 256, 0, stream>>>(x, xT, xtf, count, lossac);
  prep_cb_kernel<<<KCODE / 64, 256, 0, stream>>>(cb, cbf, rnorm);
  simfused_kernel<<<NTOK / 64, 512, 0, stream>>>(xtf, cbf, count, cand);
  rescore_kernel<<<NTOK / 4, 256, 0, stream>>>(xT, cb, count, cand, besti);
  epilogue_kernel<<<NTOK / 64, 256, 0, stream>>>(x, cb, rnorm, besti, out,
                                                 lossac);
  finalize_kernel<<<1, 1, 0, stream>>>(lossac, out + (out_size - 1));
}